// Round 15
// baseline (267.066 us; speedup 1.0000x reference)
//
#include <hip/hip_runtime.h>
#include <hip/hip_bf16.h>

#define BB    128
#define CIN   256
#define COUT  256
#define NN    64
#define KW    5
#define DIRR  16
#define ZTOT  (BB*NN)
#define SX    264   // xs row stride (bf16): 528 B = 33*16 -> odd 16B-slot stride

typedef __attribute__((ext_vector_type(4))) float f32x4;
typedef __attribute__((ext_vector_type(8))) short s16x8;

__device__ inline ushort f2bf(float f) {
    __hip_bfloat16 h = __float2bfloat16(f);
    return *(const ushort*)&h;
}
__device__ inline float bf2f(ushort u) {
    union { unsigned int ui; float f; } cv; cv.ui = ((unsigned int)u) << 16;
    return cv.f;
}
__device__ inline float wave_sum(float v) {
    #pragma unroll
    for (int o = 32; o > 0; o >>= 1) v += __shfl_down(v, o, 64);
    return v;
}
__device__ inline float silu(float x) { return x / (1.f + __expf(-x)); }

// ---------------------------------------------------------------------------
// K0: pack ALL weights in one launch.
// ---------------------------------------------------------------------------
__global__ __launch_bounds__(256) void pack_all_k(const float* __restrict__ w,
                                                  const float* __restrict__ gw,
                                                  const float* __restrict__ tg,
                                                  const float* __restrict__ fg,
                                                  ushort* __restrict__ wb,
                                                  ushort* __restrict__ gwb,
                                                  ushort* __restrict__ tgb,
                                                  ushort* __restrict__ fgTb)
{
    int idx = blockIdx.x * 256 + threadIdx.x;
    if (idx < 1310720) {
        int cl = idx & 31;
        int c  = (idx >> 5) & 255;
        int ch = (idx >> 13) & 7;
        int k  = (idx >> 16) % 5;
        int l  = idx / 327680;
        int cin = ch * 32 + cl;
        wb[idx] = f2bf(w[(((size_t)(l * COUT + c) * CIN) + cin) * KW + k]);
        return;
    }
    int j2 = idx - 1310720;
    if (j2 < 65536) {
        gwb[j2] = f2bf(gw[j2]);
    } else if (j2 < 66560) {
        int j = j2 - 65536;
        tgb[j] = f2bf(tg[j]);
    } else if (j2 < 67584) {
        int j = j2 - 66560;                        // j = p*16 + i
        int p = j >> 4, i = j & 15;
        fgTb[i * 64 + p] = f2bf(fg[j]);
    }
}

// ---------------------------------------------------------------------------
// K1: per-(b,i) conv as bf16 MFMA GEMM. [r12-exact: measured 148 us]
// A in LDS (one barrier); B direct global->VGPR, 1-step register prefetch.
// ---------------------------------------------------------------------------
__global__ __launch_bounds__(256, 4) void conv_mfma_k(const float* __restrict__ x,
                                                      const ushort* __restrict__ wb,
                                                      const float* __restrict__ bias,
                                                      ushort* __restrict__ hbuf)
{
    __shared__ __align__(16) ushort xs[68 * SX];        // ~35.9 KB

    const int tid  = threadIdx.x;
    const int lane = tid & 63;
    const int wid  = tid >> 6;
    const int blk  = blockIdx.x;
    const int b = blk >> 4, i = blk & 15;
    const int l = (i == 0) ? 0 : (i < 4) ? 1 : (i < 9) ? 2 : 3;

    // ---- stage x[b,:,i,:] transposed -> xs[2+n][cin], cin-major lanes
    {
        const float4* xb = (const float4*)(x + (((size_t)b * CIN) * DIRR + i) * NN);
        #pragma unroll
        for (int p = 0; p < 16; ++p) {
            int cin = (tid & 63) | ((p & 3) << 6);
            int nq  = ((tid >> 6) << 2) | (p >> 2);
            float4 v = xb[(size_t)cin * (DIRR * NN / 4) + nq];
            ushort* dst = xs + (size_t)(2 + nq * 4) * SX + cin;
            dst[0]      = f2bf(v.x);
            dst[SX]     = f2bf(v.y);
            dst[2 * SX] = f2bf(v.z);
            dst[3 * SX] = f2bf(v.w);
        }
        xs[ 0 * SX + tid] = 0; xs[ 1 * SX + tid] = 0;
        xs[66 * SX + tid] = 0; xs[67 * SX + tid] = 0;
    }
    __syncthreads();                                    // the ONLY barrier

    f32x4 acc[4][4];
    #pragma unroll
    for (int m = 0; m < 4; ++m)
        #pragma unroll
        for (int j = 0; j < 4; ++j) acc[m][j] = (f32x4){0.f, 0.f, 0.f, 0.f};

    const int kb = lane >> 4;
    const int lr = lane & 15;

    const ushort* wl = wb + (size_t)l * (40 * 8192);
    int boffB[4];
    #pragma unroll
    for (int j = 0; j < 4; ++j)
        boffB[j] = (wid * 64 + j * 16 + lr) * 32 + kb * 8;

    const ushort* arow = xs + (size_t)lr * SX + kb * 8;

    s16x8 bva[4], bvb[4];
    {
        const ushort* bt = wl;
        #pragma unroll
        for (int j = 0; j < 4; ++j) bva[j] = *(const s16x8*)(bt + boffB[j]);
    }

    #pragma unroll 1
    for (int t = 0; t < 40; t += 2) {
        {
            const ushort* bt = wl + ((size_t)(t + 1) << 13);
            #pragma unroll
            for (int j = 0; j < 4; ++j) bvb[j] = *(const s16x8*)(bt + boffB[j]);
        }
        {
            const ushort* ab = arow + (size_t)(t >> 3) * SX + (t & 7) * 32;
            s16x8 av[4];
            #pragma unroll
            for (int m = 0; m < 4; ++m)
                av[m] = *(const s16x8*)(ab + (size_t)m * 16 * SX);
            #pragma unroll
            for (int m = 0; m < 4; ++m)
                #pragma unroll
                for (int j = 0; j < 4; ++j)
                    acc[m][j] = __builtin_amdgcn_mfma_f32_16x16x32_bf16(av[m], bva[j], acc[m][j], 0, 0, 0);
        }
        if (t + 2 < 40) {
            const ushort* bt = wl + ((size_t)(t + 2) << 13);
            #pragma unroll
            for (int j = 0; j < 4; ++j) bva[j] = *(const s16x8*)(bt + boffB[j]);
        }
        {
            int t1 = t + 1;
            const ushort* ab = arow + (size_t)(t1 >> 3) * SX + (t1 & 7) * 32;
            s16x8 av[4];
            #pragma unroll
            for (int m = 0; m < 4; ++m)
                av[m] = *(const s16x8*)(ab + (size_t)m * 16 * SX);
            #pragma unroll
            for (int m = 0; m < 4; ++m)
                #pragma unroll
                for (int j = 0; j < 4; ++j)
                    acc[m][j] = __builtin_amdgcn_mfma_f32_16x16x32_bf16(av[m], bvb[j], acc[m][j], 0, 0, 0);
        }
    }

    // ---- epilogue: bias (i==0) + bf16 store. D: col=lane&15, row=(lane>>4)*4+r
    const int row0 = (lane >> 4) * 4;
    #pragma unroll
    for (int j = 0; j < 4; ++j) {
        int c = wid * 64 + j * 16 + lr;
        float bvv = (i == 0) ? bias[c] : 0.f;
        #pragma unroll
        for (int m = 0; m < 4; ++m)
            #pragma unroll
            for (int r = 0; r < 4; ++r) {
                int n = m * 16 + row0 + r;
                size_t z = (size_t)b * NN + n;
                hbuf[(z * DIRR + i) * COUT + c] = f2bf(acc[m][j][r] + bvv);
            }
    }
}

// ---------------------------------------------------------------------------
// K2a: norm (4 z per block) + FUSED gate GEMM.
// Writes hn2[c][z][i] bf16 and out[b, c*16+0, n] = silu(h0 @ gw^T + gb).
// Gate: h0 staged to LDS [16][264] (rows 4-15 zero; MFMA D-rows depend only
// on same A-row, so garbage-free). Only kb==0 lanes hold valid D rows 0-3.
// ---------------------------------------------------------------------------
__global__ __launch_bounds__(256) void norm_k(const ushort* __restrict__ hbuf,
                                              const float* __restrict__ afw,
                                              const ushort* __restrict__ gwb,
                                              const float* __restrict__ gb,
                                              ushort* __restrict__ hn2,
                                              float* __restrict__ out)
{
    __shared__ float red[16];
    __shared__ __align__(16) ushort h0s[16 * 264];   // padded stride: conflict-free A-reads
    const int z0 = blockIdx.x * 4;
    const int c = threadIdx.x;
    const int lane = c & 63, w = c >> 6;
    const int lr = lane & 15, kb = lane >> 4;

    // zero h0s (rows 0-3 overwritten later; barriers below order this)
    #pragma unroll
    for (int q = 0; q < 17; ++q) {
        int idx = q * 256 + c;
        if (idx < 16 * 264) h0s[idx] = 0;
    }

    float hv[4][16];
    #pragma unroll
    for (int zz = 0; zz < 4; ++zz)
        #pragma unroll
        for (int i = 0; i < 16; ++i)
            hv[zz][i] = bf2f(hbuf[((size_t)(z0 + zz) * DIRR + i) * COUT + c]);

    float s[4];
    #pragma unroll
    for (int zz = 0; zz < 4; ++zz) s[zz] = wave_sum(hv[zz][0]);
    if (lane == 0) {
        #pragma unroll
        for (int zz = 0; zz < 4; ++zz) red[zz * 4 + w] = s[zz];
    }
    __syncthreads();
    #pragma unroll
    for (int zz = 0; zz < 4; ++zz) {
        float m = (red[zz * 4] + red[zz * 4 + 1] + red[zz * 4 + 2] + red[zz * 4 + 3]) * (1.f / 256.f);
        hv[zz][0] -= m;
    }

    const float bal[4] = {0.25f, 1.f / 12.f, 1.f / 20.f, 1.f / 28.f};
    float var[4];
    #pragma unroll
    for (int zz = 0; zz < 4; ++zz) {
        float v = bal[0] * hv[zz][0] * hv[zz][0];
        #pragma unroll
        for (int i = 1; i < 16; ++i) {
            int li = (i < 4) ? 1 : (i < 9) ? 2 : 3;
            v += bal[li] * hv[zz][i] * hv[zz][i];
        }
        var[zz] = wave_sum(v);
    }
    __syncthreads();
    if (lane == 0) {
        #pragma unroll
        for (int zz = 0; zz < 4; ++zz) red[zz * 4 + w] = var[zz];
    }
    __syncthreads();
    float inv[4];
    #pragma unroll
    for (int zz = 0; zz < 4; ++zz)
        inv[zz] = rsqrtf((red[zz * 4] + red[zz * 4 + 1] + red[zz * 4 + 2] + red[zz * 4 + 3]) * (1.f / 256.f) + 1e-5f);

    float a0 = afw[c], a1 = afw[COUT + c], a2 = afw[2 * COUT + c], a3 = afw[3 * COUT + c];
    #pragma unroll
    for (int zz = 0; zz < 4; ++zz) {
        s16x8 o0, o1;
        #pragma unroll
        for (int i = 0; i < 16; ++i) {
            float al = (i == 0) ? a0 : (i < 4) ? a1 : (i < 9) ? a2 : a3;
            ushort ub = f2bf(hv[zz][i] * inv[zz] * al);
            if (i < 8) o0[i] = (short)ub; else o1[i - 8] = (short)ub;
        }
        ushort* dst = hn2 + ((size_t)c * ZTOT + z0 + zz) * DIRR;
        *(s16x8*)dst = o0;
        *(s16x8*)(dst + 8) = o1;
        h0s[zz * 264 + c] = (ushort)(unsigned short)o0[0];
    }
    __syncthreads();                 // h0s complete (incl. zero rows) before gate reads

    // ---- fused gate GEMM: M=4(z, in 16-pad), N=256, K=256 ----
    f32x4 gacc[4];
    #pragma unroll
    for (int j = 0; j < 4; ++j) gacc[j] = (f32x4){0.f, 0.f, 0.f, 0.f};
    #pragma unroll
    for (int ks = 0; ks < 8; ++ks) {
        s16x8 ga = *(const s16x8*)(h0s + lr * 264 + ks * 32 + kb * 8);
        #pragma unroll
        for (int j = 0; j < 4; ++j) {
            s16x8 gbv = *(const s16x8*)(gwb + ((size_t)(w * 64 + j * 16 + lr) * 256 + ks * 32 + kb * 8));
            gacc[j] = __builtin_amdgcn_mfma_f32_16x16x32_bf16(ga, gbv, gacc[j], 0, 0, 0);
        }
    }
    if (kb == 0) {                   // D rows 0-3 live in kb==0 lanes
        int bb = z0 >> 6, n0 = z0 & 63;
        #pragma unroll
        for (int j = 0; j < 4; ++j) {
            int cp = w * 64 + j * 16 + lr;
            float g0 = gb[cp];
            #pragma unroll
            for (int r = 0; r < 4; ++r)
                out[((size_t)bb * COUT + cp) * (DIRR * NN) + (n0 + r)] = silu(gacc[j][r] + g0);
        }
    }
}

// ---------------------------------------------------------------------------
// K2c: grid einsums batched over c. Block = (c, 256-z tile), 4 waves. [r12]
// ---------------------------------------------------------------------------
__global__ __launch_bounds__(256) void grid_k(const ushort* __restrict__ hn2,
                                              const ushort* __restrict__ tgb,
                                              const ushort* __restrict__ fgTb,
                                              float* __restrict__ out)
{
    __shared__ __align__(16) char lds[36864 + 2048 + 2304];
    ushort* P_s  = (ushort*)lds;                    // [256][72] bf16
    float*  S_s  = (float*)lds;                     // [256][17] f32 (aliases P_s)
    ushort* tg_s = (ushort*)(lds + 36864);          // [64][16]
    ushort* fgT_s= (ushort*)(lds + 36864 + 2048);   // [16][72]

    const int bid = blockIdx.x;
    const int c  = bid & 255;
    const int zt = bid >> 8;
    const int z0 = zt * 256;
    const int tid = threadIdx.x;
    const int lane = tid & 63, w = tid >> 6;
    const int lr = lane & 15, kb = lane >> 4;

    #pragma unroll
    for (int q = 0; q < 4; ++q) {
        int idx = q * 256 + tid;            // 1024
        tg_s[idx] = tgb[idx];
        int i = idx >> 6, p = idx & 63;
        fgT_s[i * 72 + p] = fgTb[idx];
    }
    __syncthreads();

    // ---- GEMM1 ----
    f32x4 acc[4][4];
    #pragma unroll
    for (int m = 0; m < 4; ++m)
        #pragma unroll
        for (int n = 0; n < 4; ++n) acc[m][n] = (f32x4){0.f, 0.f, 0.f, 0.f};

    s16x8 bv[4];
    #pragma unroll
    for (int n = 0; n < 4; ++n)
        bv[n] = (kb < 2) ? *(const s16x8*)(tg_s + (n * 16 + lr) * 16 + kb * 8)
                         : (s16x8){0,0,0,0,0,0,0,0};
    #pragma unroll
    for (int m = 0; m < 4; ++m) {
        int zl = w * 64 + m * 16 + lr;
        s16x8 av = (kb < 2) ? *(const s16x8*)(hn2 + ((size_t)c * ZTOT + z0 + zl) * DIRR + kb * 8)
                            : (s16x8){0,0,0,0,0,0,0,0};
        #pragma unroll
        for (int n = 0; n < 4; ++n)
            acc[m][n] = __builtin_amdgcn_mfma_f32_16x16x32_bf16(av, bv[n], acc[m][n], 0, 0, 0);
    }

    // ---- silu -> P_s (wave-local region) ----
    #pragma unroll
    for (int m = 0; m < 4; ++m)
        #pragma unroll
        for (int n = 0; n < 4; ++n)
            #pragma unroll
            for (int r = 0; r < 4; ++r) {
                int zl = w * 64 + m * 16 + kb * 4 + r;
                int p  = n * 16 + lr;
                P_s[zl * 72 + p] = f2bf(silu(acc[m][n][r]));
            }

    // ---- GEMM2 (reads only this wave's P_s rows; in-wave DS ordering) ----
    f32x4 acc2[4];
    #pragma unroll
    for (int m = 0; m < 4; ++m) acc2[m] = (f32x4){0.f, 0.f, 0.f, 0.f};
    #pragma unroll
    for (int ks = 0; ks < 2; ++ks) {
        s16x8 bv2 = *(const s16x8*)(fgT_s + lr * 72 + ks * 32 + kb * 8);
        #pragma unroll
        for (int m = 0; m < 4; ++m) {
            s16x8 av2 = *(const s16x8*)(P_s + (w * 64 + m * 16 + lr) * 72 + ks * 32 + kb * 8);
            acc2[m] = __builtin_amdgcn_mfma_f32_16x16x32_bf16(av2, bv2, acc2[m], 0, 0, 0);
        }
    }

    __syncthreads();        // all waves done with P_s before S_s overwrites it

    #pragma unroll
    for (int m = 0; m < 4; ++m)
        #pragma unroll
        for (int r = 0; r < 4; ++r) {
            int zl = w * 64 + m * 16 + kb * 4 + r;
            S_s[zl * 17 + lr] = acc2[m][r];
        }
    __syncthreads();

    // ---- coalesced output: i = 1..15 ----
    const int bb = tid >> 6, n = tid & 63;
    const int b0 = zt * 4;
    const float* srow = S_s + (bb * 64 + n) * 17;
    float* obase = out + ((size_t)(b0 + bb) * COUT + c) * (DIRR * NN) + n;
    #pragma unroll
    for (int i = 1; i < 16; ++i)
        obase[i * NN] = srow[i];
}

// ---------------------------------------------------------------------------
// Fallback K2 (round-2 proven) if ws_size is too small for the split path.
// ---------------------------------------------------------------------------
__global__ __launch_bounds__(256) void post_k(const ushort* __restrict__ hbuf,
                                              const float* __restrict__ afw,
                                              const float* __restrict__ gw,
                                              const float* __restrict__ gb,
                                              const float* __restrict__ tg,
                                              const float* __restrict__ fg,
                                              float* __restrict__ out)
{
    __shared__ float h0s[COUT];
    __shared__ float red[4];
    __shared__ float tgs[64 * 16];
    __shared__ float fgs[64 * 16];

    int z = blockIdx.x;
    int c = threadIdx.x;
    int b = z >> 6, n = z & 63;
    int lane = c & 63, wid = c >> 6;

    for (int idx = c; idx < 1024; idx += 256) { tgs[idx] = tg[idx]; fgs[idx] = fg[idx]; }

    float hv[16];
    #pragma unroll
    for (int i = 0; i < 16; ++i)
        hv[i] = bf2f(hbuf[((size_t)z * DIRR + i) * COUT + c]);

    float s0 = wave_sum(hv[0]);
    if (lane == 0) red[wid] = s0;
    __syncthreads();
    float mean0 = (red[0] + red[1] + red[2] + red[3]) * (1.f / 256.f);
    hv[0] -= mean0;

    const float bal[4] = {0.25f, 1.f / 12.f, 1.f / 20.f, 1.f / 28.f};
    float var = bal[0] * hv[0] * hv[0];
    #pragma unroll
    for (int i = 1; i < 16; ++i) {
        int li = (i < 4) ? 1 : (i < 9) ? 2 : 3;
        var += bal[li] * hv[i] * hv[i];
    }
    float s1 = wave_sum(var);
    __syncthreads();
    if (lane == 0) red[wid] = s1;
    __syncthreads();
    float inv = rsqrtf((red[0] + red[1] + red[2] + red[3]) * (1.f / 256.f) + 1e-5f);

    float a0 = afw[c], a1 = afw[COUT + c], a2 = afw[2 * COUT + c], a3 = afw[3 * COUT + c];
    #pragma unroll
    for (int i = 0; i < 16; ++i) {
        float al = (i == 0) ? a0 : (i < 4) ? a1 : (i < 9) ? a2 : a3;
        hv[i] *= inv * al;
    }
    h0s[c] = hv[0];
    __syncthreads();

    float g = gb[c];
    const float4* gwr = (const float4*)(gw + (size_t)c * COUT);
    #pragma unroll 4
    for (int j = 0; j < 64; ++j) {
        float4 wv = gwr[j];
        g += h0s[4 * j] * wv.x + h0s[4 * j + 1] * wv.y + h0s[4 * j + 2] * wv.z + h0s[4 * j + 3] * wv.w;
    }
    float gate = silu(g);

    float s2a[16];
    #pragma unroll
    for (int i = 0; i < 16; ++i) s2a[i] = 0.f;
    #pragma unroll 1
    for (int p = 0; p < 64; ++p) {
        float gv = 0.f;
        #pragma unroll
        for (int i = 0; i < 16; ++i) gv += tgs[p * 16 + i] * hv[i];
        gv = silu(gv);
        #pragma unroll
        for (int i = 0; i < 16; ++i) s2a[i] += fgs[p * 16 + i] * gv;
    }

    float* ob = out + (size_t)b * COUT * DIRR * NN + (size_t)c * DIRR * NN + n;
    ob[0] = gate;
    #pragma unroll
    for (int i = 1; i < 16; ++i) ob[i * NN] = s2a[i];
}

extern "C" void kernel_launch(void* const* d_in, const int* in_sizes, int n_in,
                              void* d_out, int out_size, void* d_ws, size_t ws_size,
                              hipStream_t stream)
{
    const float* x    = (const float*)d_in[0];
    const float* w    = (const float*)d_in[1];
    const float* bias = (const float*)d_in[2];
    const float* afw  = (const float*)d_in[3];
    const float* gw   = (const float*)d_in[4];
    const float* gb   = (const float*)d_in[5];
    const float* tg   = (const float*)d_in[6];
    const float* fg   = (const float*)d_in[7];
    float* out = (float*)d_out;

    const size_t off_hbuf = 0;                         // 64 MiB
    const size_t off_wb   = 67108864;                  // 2.62 MiB
    const size_t off_hn2  = 69730304;                  // 64 MiB
    const size_t off_hn0  = off_hn2 + 67108864;        // 4 MiB (unused, kept for layout)
    const size_t off_gwb  = off_hn0 + 4194304;         // 128 KiB
    const size_t off_tgb  = off_gwb + 131072;          // 2 KiB
    const size_t off_fgT  = off_tgb + 2048;            // 2 KiB
    const size_t need     = off_fgT + 2048;            // ~134.6 MiB

    ushort* hbuf = (ushort*)((char*)d_ws + off_hbuf);
    ushort* wb   = (ushort*)((char*)d_ws + off_wb);

    if (ws_size >= need) {
        ushort* hn2  = (ushort*)((char*)d_ws + off_hn2);
        ushort* gwb  = (ushort*)((char*)d_ws + off_gwb);
        ushort* tgb  = (ushort*)((char*)d_ws + off_tgb);
        ushort* fgTb = (ushort*)((char*)d_ws + off_fgT);

        pack_all_k <<<5384, 256, 0, stream>>>(w, gw, tg, fg, wb, gwb, tgb, fgTb);
        conv_mfma_k<<<BB * DIRR, 256, 0, stream>>>(x, wb, bias, hbuf);
        norm_k     <<<ZTOT / 4, 256, 0, stream>>>(hbuf, afw, gwb, gb, hn2, out);
        grid_k     <<<256 * (ZTOT / 256), 256, 0, stream>>>(hn2, tgb, fgTb, out);
    } else {
        pack_all_k <<<5120, 256, 0, stream>>>(w, gw, tg, fg, wb,
                                              (ushort*)((char*)d_ws + off_wb),
                                              (ushort*)((char*)d_ws + off_wb),
                                              (ushort*)((char*)d_ws + off_wb));
        conv_mfma_k<<<BB * DIRR, 256, 0, stream>>>(x, wb, bias, hbuf);
        post_k     <<<ZTOT, 256, 0, stream>>>(hbuf, afw, gw, gb, tg, fg, out);
    }
}

// Round 16
// 253.937 us; speedup vs baseline: 1.0517x; 1.0517x over previous
//
#include <hip/hip_runtime.h>
#include <hip/hip_bf16.h>

#define BB    128
#define CIN   256
#define COUT  256
#define NN    64
#define KW    5
#define DIRR  16
#define ZTOT  (BB*NN)
#define SX    264   // xs row stride (bf16): 528 B = 33*16 -> odd 16B-slot stride

typedef __attribute__((ext_vector_type(4))) float f32x4;
typedef __attribute__((ext_vector_type(8))) short s16x8;

__device__ inline ushort f2bf(float f) {
    __hip_bfloat16 h = __float2bfloat16(f);
    return *(const ushort*)&h;
}
__device__ inline float bf2f(ushort u) {
    union { unsigned int ui; float f; } cv; cv.ui = ((unsigned int)u) << 16;
    return cv.f;
}
__device__ inline float wave_sum(float v) {
    #pragma unroll
    for (int o = 32; o > 0; o >>= 1) v += __shfl_down(v, o, 64);
    return v;
}
__device__ inline float silu(float x) { return x / (1.f + __expf(-x)); }

// ---------------------------------------------------------------------------
// K0: pack ALL weights in one launch.
// ---------------------------------------------------------------------------
__global__ __launch_bounds__(256) void pack_all_k(const float* __restrict__ w,
                                                  const float* __restrict__ gw,
                                                  const float* __restrict__ tg,
                                                  const float* __restrict__ fg,
                                                  ushort* __restrict__ wb,
                                                  ushort* __restrict__ gwb,
                                                  ushort* __restrict__ tgb,
                                                  ushort* __restrict__ fgTb)
{
    int idx = blockIdx.x * 256 + threadIdx.x;
    if (idx < 1310720) {
        int cl = idx & 31;
        int c  = (idx >> 5) & 255;
        int ch = (idx >> 13) & 7;
        int k  = (idx >> 16) % 5;
        int l  = idx / 327680;
        int cin = ch * 32 + cl;
        wb[idx] = f2bf(w[(((size_t)(l * COUT + c) * CIN) + cin) * KW + k]);
        return;
    }
    int j2 = idx - 1310720;
    if (j2 < 65536) {
        gwb[j2] = f2bf(gw[j2]);
    } else if (j2 < 66560) {
        int j = j2 - 65536;
        tgb[j] = f2bf(tg[j]);
    } else if (j2 < 67584) {
        int j = j2 - 66560;                        // j = p*16 + i
        int p = j >> 4, i = j & 15;
        fgTb[i * 64 + p] = f2bf(fg[j]);
    }
}

// ---------------------------------------------------------------------------
// K1: per-(b,i) conv as bf16 MFMA GEMM. [r12-exact: measured 148 us]
// A in LDS (one barrier); B direct global->VGPR, 1-step register prefetch.
// ---------------------------------------------------------------------------
__global__ __launch_bounds__(256, 4) void conv_mfma_k(const float* __restrict__ x,
                                                      const ushort* __restrict__ wb,
                                                      const float* __restrict__ bias,
                                                      ushort* __restrict__ hbuf)
{
    __shared__ __align__(16) ushort xs[68 * SX];        // ~35.9 KB

    const int tid  = threadIdx.x;
    const int lane = tid & 63;
    const int wid  = tid >> 6;
    const int blk  = blockIdx.x;
    const int b = blk >> 4, i = blk & 15;
    const int l = (i == 0) ? 0 : (i < 4) ? 1 : (i < 9) ? 2 : 3;

    // ---- stage x[b,:,i,:] transposed -> xs[2+n][cin], cin-major lanes
    {
        const float4* xb = (const float4*)(x + (((size_t)b * CIN) * DIRR + i) * NN);
        #pragma unroll
        for (int p = 0; p < 16; ++p) {
            int cin = (tid & 63) | ((p & 3) << 6);
            int nq  = ((tid >> 6) << 2) | (p >> 2);
            float4 v = xb[(size_t)cin * (DIRR * NN / 4) + nq];
            ushort* dst = xs + (size_t)(2 + nq * 4) * SX + cin;
            dst[0]      = f2bf(v.x);
            dst[SX]     = f2bf(v.y);
            dst[2 * SX] = f2bf(v.z);
            dst[3 * SX] = f2bf(v.w);
        }
        xs[ 0 * SX + tid] = 0; xs[ 1 * SX + tid] = 0;
        xs[66 * SX + tid] = 0; xs[67 * SX + tid] = 0;
    }
    __syncthreads();                                    // the ONLY barrier

    f32x4 acc[4][4];
    #pragma unroll
    for (int m = 0; m < 4; ++m)
        #pragma unroll
        for (int j = 0; j < 4; ++j) acc[m][j] = (f32x4){0.f, 0.f, 0.f, 0.f};

    const int kb = lane >> 4;
    const int lr = lane & 15;

    const ushort* wl = wb + (size_t)l * (40 * 8192);
    int boffB[4];
    #pragma unroll
    for (int j = 0; j < 4; ++j)
        boffB[j] = (wid * 64 + j * 16 + lr) * 32 + kb * 8;

    const ushort* arow = xs + (size_t)lr * SX + kb * 8;

    s16x8 bva[4], bvb[4];
    {
        const ushort* bt = wl;
        #pragma unroll
        for (int j = 0; j < 4; ++j) bva[j] = *(const s16x8*)(bt + boffB[j]);
    }

    #pragma unroll 1
    for (int t = 0; t < 40; t += 2) {
        {
            const ushort* bt = wl + ((size_t)(t + 1) << 13);
            #pragma unroll
            for (int j = 0; j < 4; ++j) bvb[j] = *(const s16x8*)(bt + boffB[j]);
        }
        {
            const ushort* ab = arow + (size_t)(t >> 3) * SX + (t & 7) * 32;
            s16x8 av[4];
            #pragma unroll
            for (int m = 0; m < 4; ++m)
                av[m] = *(const s16x8*)(ab + (size_t)m * 16 * SX);
            #pragma unroll
            for (int m = 0; m < 4; ++m)
                #pragma unroll
                for (int j = 0; j < 4; ++j)
                    acc[m][j] = __builtin_amdgcn_mfma_f32_16x16x32_bf16(av[m], bva[j], acc[m][j], 0, 0, 0);
        }
        if (t + 2 < 40) {
            const ushort* bt = wl + ((size_t)(t + 2) << 13);
            #pragma unroll
            for (int j = 0; j < 4; ++j) bva[j] = *(const s16x8*)(bt + boffB[j]);
        }
        {
            int t1 = t + 1;
            const ushort* ab = arow + (size_t)(t1 >> 3) * SX + (t1 & 7) * 32;
            s16x8 av[4];
            #pragma unroll
            for (int m = 0; m < 4; ++m)
                av[m] = *(const s16x8*)(ab + (size_t)m * 16 * SX);
            #pragma unroll
            for (int m = 0; m < 4; ++m)
                #pragma unroll
                for (int j = 0; j < 4; ++j)
                    acc[m][j] = __builtin_amdgcn_mfma_f32_16x16x32_bf16(av[m], bvb[j], acc[m][j], 0, 0, 0);
        }
    }

    // ---- epilogue: bias (i==0) + bf16 store. D: col=lane&15, row=(lane>>4)*4+r
    const int row0 = (lane >> 4) * 4;
    #pragma unroll
    for (int j = 0; j < 4; ++j) {
        int c = wid * 64 + j * 16 + lr;
        float bvv = (i == 0) ? bias[c] : 0.f;
        #pragma unroll
        for (int m = 0; m < 4; ++m)
            #pragma unroll
            for (int r = 0; r < 4; ++r) {
                int n = m * 16 + row0 + r;
                size_t z = (size_t)b * NN + n;
                hbuf[(z * DIRR + i) * COUT + c] = f2bf(acc[m][j][r] + bvv);
            }
    }
}

// ---------------------------------------------------------------------------
// K2a: norm, 4 z per block (2048 blocks). Writes hn2[c][z][i] + hn0[z][c].
// ---------------------------------------------------------------------------
__global__ __launch_bounds__(256) void norm_k(const ushort* __restrict__ hbuf,
                                              const float* __restrict__ afw,
                                              ushort* __restrict__ hn2,
                                              ushort* __restrict__ hn0)
{
    __shared__ float red[16];
    const int z0 = blockIdx.x * 4;
    const int c = threadIdx.x;
    const int lane = c & 63, w = c >> 6;

    float hv[4][16];
    #pragma unroll
    for (int zz = 0; zz < 4; ++zz)
        #pragma unroll
        for (int i = 0; i < 16; ++i)
            hv[zz][i] = bf2f(hbuf[((size_t)(z0 + zz) * DIRR + i) * COUT + c]);

    float s[4];
    #pragma unroll
    for (int zz = 0; zz < 4; ++zz) s[zz] = wave_sum(hv[zz][0]);
    if (lane == 0) {
        #pragma unroll
        for (int zz = 0; zz < 4; ++zz) red[zz * 4 + w] = s[zz];
    }
    __syncthreads();
    #pragma unroll
    for (int zz = 0; zz < 4; ++zz) {
        float m = (red[zz * 4] + red[zz * 4 + 1] + red[zz * 4 + 2] + red[zz * 4 + 3]) * (1.f / 256.f);
        hv[zz][0] -= m;
    }

    const float bal[4] = {0.25f, 1.f / 12.f, 1.f / 20.f, 1.f / 28.f};
    float var[4];
    #pragma unroll
    for (int zz = 0; zz < 4; ++zz) {
        float v = bal[0] * hv[zz][0] * hv[zz][0];
        #pragma unroll
        for (int i = 1; i < 16; ++i) {
            int li = (i < 4) ? 1 : (i < 9) ? 2 : 3;
            v += bal[li] * hv[zz][i] * hv[zz][i];
        }
        var[zz] = wave_sum(v);
    }
    __syncthreads();
    if (lane == 0) {
        #pragma unroll
        for (int zz = 0; zz < 4; ++zz) red[zz * 4 + w] = var[zz];
    }
    __syncthreads();
    float inv[4];
    #pragma unroll
    for (int zz = 0; zz < 4; ++zz)
        inv[zz] = rsqrtf((red[zz * 4] + red[zz * 4 + 1] + red[zz * 4 + 2] + red[zz * 4 + 3]) * (1.f / 256.f) + 1e-5f);

    float a0 = afw[c], a1 = afw[COUT + c], a2 = afw[2 * COUT + c], a3 = afw[3 * COUT + c];
    #pragma unroll
    for (int zz = 0; zz < 4; ++zz) {
        s16x8 o0, o1;
        #pragma unroll
        for (int i = 0; i < 16; ++i) {
            float al = (i == 0) ? a0 : (i < 4) ? a1 : (i < 9) ? a2 : a3;
            ushort ub = f2bf(hv[zz][i] * inv[zz] * al);
            if (i < 8) o0[i] = (short)ub; else o1[i - 8] = (short)ub;
        }
        ushort* dst = hn2 + ((size_t)c * ZTOT + z0 + zz) * DIRR;
        *(s16x8*)dst = o0;
        *(s16x8*)(dst + 8) = o1;
        hn0[(size_t)(z0 + zz) * COUT + c] = (ushort)(unsigned short)o0[0];
    }
}

// ---------------------------------------------------------------------------
// K2b: gate GEMM — gate[z,c] = silu(hn0[z,:] @ gwb[c,:] + gb[c]) -> out i=0.
// ---------------------------------------------------------------------------
__global__ __launch_bounds__(256) void gate_k(const ushort* __restrict__ hn0,
                                              const ushort* __restrict__ gwb,
                                              const float* __restrict__ gb,
                                              float* __restrict__ out)
{
    const int b = blockIdx.x;
    const int tid = threadIdx.x;
    const int lane = tid & 63, w = tid >> 6;
    const int lr = lane & 15, kb = lane >> 4;

    f32x4 acc[4][4];
    #pragma unroll
    for (int m = 0; m < 4; ++m)
        #pragma unroll
        for (int n = 0; n < 4; ++n) acc[m][n] = (f32x4){0.f, 0.f, 0.f, 0.f};

    #pragma unroll 1
    for (int ks = 0; ks < 8; ++ks) {
        s16x8 av[4], bv[4];
        #pragma unroll
        for (int m = 0; m < 4; ++m)
            av[m] = *(const s16x8*)(hn0 + ((size_t)(b * 64 + m * 16 + lr) * 256 + ks * 32 + kb * 8));
        #pragma unroll
        for (int n = 0; n < 4; ++n)
            bv[n] = *(const s16x8*)(gwb + ((size_t)(w * 64 + n * 16 + lr) * 256 + ks * 32 + kb * 8));
        #pragma unroll
        for (int m = 0; m < 4; ++m)
            #pragma unroll
            for (int n = 0; n < 4; ++n)
                acc[m][n] = __builtin_amdgcn_mfma_f32_16x16x32_bf16(av[m], bv[n], acc[m][n], 0, 0, 0);
    }

    #pragma unroll
    for (int n = 0; n < 4; ++n) {
        int c = w * 64 + n * 16 + lr;
        float gbc = gb[c];
        #pragma unroll
        for (int m = 0; m < 4; ++m)
            #pragma unroll
            for (int r = 0; r < 4; ++r) {
                int nrow = m * 16 + kb * 4 + r;
                out[((size_t)b * COUT + c) * (DIRR * NN) + nrow] = silu(acc[m][n][r] + gbc);
            }
    }
}

// ---------------------------------------------------------------------------
// K2c: grid einsums batched over c. Block = (c, 256-z tile), 4 waves. [r12]
// ---------------------------------------------------------------------------
__global__ __launch_bounds__(256) void grid_k(const ushort* __restrict__ hn2,
                                              const ushort* __restrict__ tgb,
                                              const ushort* __restrict__ fgTb,
                                              float* __restrict__ out)
{
    __shared__ __align__(16) char lds[36864 + 2048 + 2304];
    ushort* P_s  = (ushort*)lds;                    // [256][72] bf16
    float*  S_s  = (float*)lds;                     // [256][17] f32 (aliases P_s)
    ushort* tg_s = (ushort*)(lds + 36864);          // [64][16]
    ushort* fgT_s= (ushort*)(lds + 36864 + 2048);   // [16][72]

    const int bid = blockIdx.x;
    const int c  = bid & 255;
    const int zt = bid >> 8;
    const int z0 = zt * 256;
    const int tid = threadIdx.x;
    const int lane = tid & 63, w = tid >> 6;
    const int lr = lane & 15, kb = lane >> 4;

    #pragma unroll
    for (int q = 0; q < 4; ++q) {
        int idx = q * 256 + tid;            // 1024
        tg_s[idx] = tgb[idx];
        int i = idx >> 6, p = idx & 63;
        fgT_s[i * 72 + p] = fgTb[idx];
    }
    __syncthreads();

    // ---- GEMM1 ----
    f32x4 acc[4][4];
    #pragma unroll
    for (int m = 0; m < 4; ++m)
        #pragma unroll
        for (int n = 0; n < 4; ++n) acc[m][n] = (f32x4){0.f, 0.f, 0.f, 0.f};

    s16x8 bv[4];
    #pragma unroll
    for (int n = 0; n < 4; ++n)
        bv[n] = (kb < 2) ? *(const s16x8*)(tg_s + (n * 16 + lr) * 16 + kb * 8)
                         : (s16x8){0,0,0,0,0,0,0,0};
    #pragma unroll
    for (int m = 0; m < 4; ++m) {
        int zl = w * 64 + m * 16 + lr;
        s16x8 av = (kb < 2) ? *(const s16x8*)(hn2 + ((size_t)c * ZTOT + z0 + zl) * DIRR + kb * 8)
                            : (s16x8){0,0,0,0,0,0,0,0};
        #pragma unroll
        for (int n = 0; n < 4; ++n)
            acc[m][n] = __builtin_amdgcn_mfma_f32_16x16x32_bf16(av, bv[n], acc[m][n], 0, 0, 0);
    }

    // ---- silu -> P_s (wave-local region) ----
    #pragma unroll
    for (int m = 0; m < 4; ++m)
        #pragma unroll
        for (int n = 0; n < 4; ++n)
            #pragma unroll
            for (int r = 0; r < 4; ++r) {
                int zl = w * 64 + m * 16 + kb * 4 + r;
                int p  = n * 16 + lr;
                P_s[zl * 72 + p] = f2bf(silu(acc[m][n][r]));
            }

    // ---- GEMM2 (reads only this wave's P_s rows; in-wave DS ordering) ----
    f32x4 acc2[4];
    #pragma unroll
    for (int m = 0; m < 4; ++m) acc2[m] = (f32x4){0.f, 0.f, 0.f, 0.f};
    #pragma unroll
    for (int ks = 0; ks < 2; ++ks) {
        s16x8 bv2 = *(const s16x8*)(fgT_s + lr * 72 + ks * 32 + kb * 8);
        #pragma unroll
        for (int m = 0; m < 4; ++m) {
            s16x8 av2 = *(const s16x8*)(P_s + (w * 64 + m * 16 + lr) * 72 + ks * 32 + kb * 8);
            acc2[m] = __builtin_amdgcn_mfma_f32_16x16x32_bf16(av2, bv2, acc2[m], 0, 0, 0);
        }
    }

    __syncthreads();        // all waves done with P_s before S_s overwrites it

    #pragma unroll
    for (int m = 0; m < 4; ++m)
        #pragma unroll
        for (int r = 0; r < 4; ++r) {
            int zl = w * 64 + m * 16 + kb * 4 + r;
            S_s[zl * 17 + lr] = acc2[m][r];
        }
    __syncthreads();

    // ---- coalesced output: i = 1..15 ----
    const int bb = tid >> 6, n = tid & 63;
    const int b0 = zt * 4;
    const float* srow = S_s + (bb * 64 + n) * 17;
    float* obase = out + ((size_t)(b0 + bb) * COUT + c) * (DIRR * NN) + n;
    #pragma unroll
    for (int i = 1; i < 16; ++i)
        obase[i * NN] = srow[i];
}

// ---------------------------------------------------------------------------
// Fallback K2 (round-2 proven) if ws_size is too small for the split path.
// ---------------------------------------------------------------------------
__global__ __launch_bounds__(256) void post_k(const ushort* __restrict__ hbuf,
                                              const float* __restrict__ afw,
                                              const float* __restrict__ gw,
                                              const float* __restrict__ gb,
                                              const float* __restrict__ tg,
                                              const float* __restrict__ fg,
                                              float* __restrict__ out)
{
    __shared__ float h0s[COUT];
    __shared__ float red[4];
    __shared__ float tgs[64 * 16];
    __shared__ float fgs[64 * 16];

    int z = blockIdx.x;
    int c = threadIdx.x;
    int b = z >> 6, n = z & 63;
    int lane = c & 63, wid = c >> 6;

    for (int idx = c; idx < 1024; idx += 256) { tgs[idx] = tg[idx]; fgs[idx] = fg[idx]; }

    float hv[16];
    #pragma unroll
    for (int i = 0; i < 16; ++i)
        hv[i] = bf2f(hbuf[((size_t)z * DIRR + i) * COUT + c]);

    float s0 = wave_sum(hv[0]);
    if (lane == 0) red[wid] = s0;
    __syncthreads();
    float mean0 = (red[0] + red[1] + red[2] + red[3]) * (1.f / 256.f);
    hv[0] -= mean0;

    const float bal[4] = {0.25f, 1.f / 12.f, 1.f / 20.f, 1.f / 28.f};
    float var = bal[0] * hv[0] * hv[0];
    #pragma unroll
    for (int i = 1; i < 16; ++i) {
        int li = (i < 4) ? 1 : (i < 9) ? 2 : 3;
        var += bal[li] * hv[i] * hv[i];
    }
    float s1 = wave_sum(var);
    __syncthreads();
    if (lane == 0) red[wid] = s1;
    __syncthreads();
    float inv = rsqrtf((red[0] + red[1] + red[2] + red[3]) * (1.f / 256.f) + 1e-5f);

    float a0 = afw[c], a1 = afw[COUT + c], a2 = afw[2 * COUT + c], a3 = afw[3 * COUT + c];
    #pragma unroll
    for (int i = 0; i < 16; ++i) {
        float al = (i == 0) ? a0 : (i < 4) ? a1 : (i < 9) ? a2 : a3;
        hv[i] *= inv * al;
    }
    h0s[c] = hv[0];
    __syncthreads();

    float g = gb[c];
    const float4* gwr = (const float4*)(gw + (size_t)c * COUT);
    #pragma unroll 4
    for (int j = 0; j < 64; ++j) {
        float4 wv = gwr[j];
        g += h0s[4 * j] * wv.x + h0s[4 * j + 1] * wv.y + h0s[4 * j + 2] * wv.z + h0s[4 * j + 3] * wv.w;
    }
    float gate = silu(g);

    float s2a[16];
    #pragma unroll
    for (int i = 0; i < 16; ++i) s2a[i] = 0.f;
    #pragma unroll 1
    for (int p = 0; p < 64; ++p) {
        float gv = 0.f;
        #pragma unroll
        for (int i = 0; i < 16; ++i) gv += tgs[p * 16 + i] * hv[i];
        gv = silu(gv);
        #pragma unroll
        for (int i = 0; i < 16; ++i) s2a[i] += fgs[p * 16 + i] * gv;
    }

    float* ob = out + (size_t)b * COUT * DIRR * NN + (size_t)c * DIRR * NN + n;
    ob[0] = gate;
    #pragma unroll
    for (int i = 1; i < 16; ++i) ob[i * NN] = s2a[i];
}

extern "C" void kernel_launch(void* const* d_in, const int* in_sizes, int n_in,
                              void* d_out, int out_size, void* d_ws, size_t ws_size,
                              hipStream_t stream)
{
    const float* x    = (const float*)d_in[0];
    const float* w    = (const float*)d_in[1];
    const float* bias = (const float*)d_in[2];
    const float* afw  = (const float*)d_in[3];
    const float* gw   = (const float*)d_in[4];
    const float* gb   = (const float*)d_in[5];
    const float* tg   = (const float*)d_in[6];
    const float* fg   = (const float*)d_in[7];
    float* out = (float*)d_out;

    const size_t off_hbuf = 0;                         // 64 MiB
    const size_t off_wb   = 67108864;                  // 2.62 MiB
    const size_t off_hn2  = 69730304;                  // 64 MiB
    const size_t off_hn0  = off_hn2 + 67108864;        // 4 MiB
    const size_t off_gwb  = off_hn0 + 4194304;         // 128 KiB
    const size_t off_tgb  = off_gwb + 131072;          // 2 KiB
    const size_t off_fgT  = off_tgb + 2048;            // 2 KiB
    const size_t need     = off_fgT + 2048;            // ~134.6 MiB

    ushort* hbuf = (ushort*)((char*)d_ws + off_hbuf);
    ushort* wb   = (ushort*)((char*)d_ws + off_wb);

    if (ws_size >= need) {
        ushort* hn2  = (ushort*)((char*)d_ws + off_hn2);
        ushort* hn0  = (ushort*)((char*)d_ws + off_hn0);
        ushort* gwb  = (ushort*)((char*)d_ws + off_gwb);
        ushort* tgb  = (ushort*)((char*)d_ws + off_tgb);
        ushort* fgTb = (ushort*)((char*)d_ws + off_fgT);

        pack_all_k <<<5384, 256, 0, stream>>>(w, gw, tg, fg, wb, gwb, tgb, fgTb);
        conv_mfma_k<<<BB * DIRR, 256, 0, stream>>>(x, wb, bias, hbuf);
        norm_k     <<<ZTOT / 4, 256, 0, stream>>>(hbuf, afw, hn2, hn0);
        gate_k     <<<BB, 256, 0, stream>>>(hn0, gwb, gb, out);
        grid_k     <<<256 * (ZTOT / 256), 256, 0, stream>>>(hn2, tgb, fgTb, out);
    } else {
        pack_all_k <<<5120, 256, 0, stream>>>(w, gw, tg, fg, wb,
                                              (ushort*)((char*)d_ws + off_wb),
                                              (ushort*)((char*)d_ws + off_wb),
                                              (ushort*)((char*)d_ws + off_wb));
        conv_mfma_k<<<BB * DIRR, 256, 0, stream>>>(x, wb, bias, hbuf);
        post_k     <<<ZTOT, 256, 0, stream>>>(hbuf, afw, gw, gb, tg, fg, out);
    }
}

// Round 17
// 248.815 us; speedup vs baseline: 1.0733x; 1.0206x over previous
//
#include <hip/hip_runtime.h>
#include <hip/hip_bf16.h>

#define BB    128
#define CIN   256
#define COUT  256
#define NN    64
#define KW    5
#define DIRR  16
#define ZTOT  (BB*NN)
#define SX    264   // xs row stride (bf16): 528 B = 33*16 -> odd 16B-slot stride

typedef __attribute__((ext_vector_type(4)))  float f32x4;
typedef __attribute__((ext_vector_type(16))) float f32x16;
typedef __attribute__((ext_vector_type(8)))  short s16x8;

__device__ inline ushort f2bf(float f) {
    __hip_bfloat16 h = __float2bfloat16(f);
    return *(const ushort*)&h;
}
__device__ inline float bf2f(ushort u) {
    union { unsigned int ui; float f; } cv; cv.ui = ((unsigned int)u) << 16;
    return cv.f;
}
__device__ inline float wave_sum(float v) {
    #pragma unroll
    for (int o = 32; o > 0; o >>= 1) v += __shfl_down(v, o, 64);
    return v;
}
__device__ inline float silu(float x) { return x / (1.f + __expf(-x)); }

// ---------------------------------------------------------------------------
// K0: pack ALL weights in one launch.
// conv w -> wb32[l][t=80][c256][cin16]  (t = shift*16 + cin-chunk16), 8KB tiles
// ---------------------------------------------------------------------------
__global__ __launch_bounds__(256) void pack_all_k(const float* __restrict__ w,
                                                  const float* __restrict__ gw,
                                                  const float* __restrict__ tg,
                                                  const float* __restrict__ fg,
                                                  ushort* __restrict__ wb,
                                                  ushort* __restrict__ gwb,
                                                  ushort* __restrict__ tgb,
                                                  ushort* __restrict__ fgTb)
{
    int idx = blockIdx.x * 256 + threadIdx.x;
    if (idx < 1310720) {
        int cl16 = idx & 15;
        int c    = (idx >> 4) & 255;
        int ch   = (idx >> 12) & 15;
        int lk   = idx >> 16;             // l*5 + k, 0..19
        int k    = lk % 5;
        int l    = lk / 5;
        int cin  = ch * 16 + cl16;
        wb[idx] = f2bf(w[(((size_t)(l * COUT + c) * CIN) + cin) * KW + k]);
        return;
    }
    int j2 = idx - 1310720;
    if (j2 < 65536) {
        gwb[j2] = f2bf(gw[j2]);
    } else if (j2 < 66560) {
        int j = j2 - 65536;
        tgb[j] = f2bf(tg[j]);
    } else if (j2 < 67584) {
        int j = j2 - 66560;                        // j = p*16 + i
        int p = j >> 4, i = j & 15;
        fgTb[i * 64 + p] = f2bf(fg[j]);
    }
}

// ---------------------------------------------------------------------------
// K1: per-(b,i) conv as bf16 MFMA GEMM, 32x32x16 variant.
// M=64(n) x N=256(c), K = 80 steps of 16 (5 shifts x 16 cin-chunks).
// A in LDS (one barrier); B direct global->VGPR, 4-set rotating prefetch
// (distance-4 in K16 units ~= 600cyc cover) at UNCHANGED 4 blocks/CU.
// ---------------------------------------------------------------------------
__global__ __launch_bounds__(256, 4) void conv_mfma_k(const float* __restrict__ x,
                                                      const ushort* __restrict__ wb,
                                                      const float* __restrict__ bias,
                                                      ushort* __restrict__ hbuf)
{
    __shared__ __align__(16) ushort xs[68 * SX];        // ~35.9 KB

    const int tid  = threadIdx.x;
    const int lane = tid & 63;
    const int wid  = tid >> 6;
    const int blk  = blockIdx.x;
    const int b = blk >> 4, i = blk & 15;
    const int l = (i == 0) ? 0 : (i < 4) ? 1 : (i < 9) ? 2 : 3;

    // ---- stage x[b,:,i,:] transposed -> xs[2+n][cin], cin-major lanes
    {
        const float4* xb = (const float4*)(x + (((size_t)b * CIN) * DIRR + i) * NN);
        #pragma unroll
        for (int p = 0; p < 16; ++p) {
            int cin = (tid & 63) | ((p & 3) << 6);
            int nq  = ((tid >> 6) << 2) | (p >> 2);
            float4 v = xb[(size_t)cin * (DIRR * NN / 4) + nq];
            ushort* dst = xs + (size_t)(2 + nq * 4) * SX + cin;
            dst[0]      = f2bf(v.x);
            dst[SX]     = f2bf(v.y);
            dst[2 * SX] = f2bf(v.z);
            dst[3 * SX] = f2bf(v.w);
        }
        xs[ 0 * SX + tid] = 0; xs[ 1 * SX + tid] = 0;
        xs[66 * SX + tid] = 0; xs[67 * SX + tid] = 0;
    }
    __syncthreads();                                    // the ONLY barrier

    f32x16 acc[2][2];
    #pragma unroll
    for (int m = 0; m < 2; ++m)
        #pragma unroll
        for (int j = 0; j < 2; ++j)
            #pragma unroll
            for (int r = 0; r < 16; ++r) acc[m][j][r] = 0.f;

    const int l31 = lane & 31;          // A-row / B-col within 32
    const int kh  = lane >> 5;          // k-octet group (0/1)

    const ushort* wl = wb + (size_t)l * (80 * 4096);
    int boffB[2];
    #pragma unroll
    for (int j = 0; j < 2; ++j)
        boffB[j] = (wid * 64 + j * 32 + l31) * 16 + kh * 8;

    const ushort* arow = xs + (size_t)l31 * SX + kh * 8;

    // step t (0..79): shift s = t>>4, cin-chunk = t&15. B tile = wl + t*4096.
    // A addr(m,t) = arow + (m*32 + (t>>4))*SX + (t&15)*16.
#define LOADB(dst, t) do {                                              \
        const ushort* bt_ = wl + ((size_t)(t) << 12);                   \
        dst##0 = *(const s16x8*)(bt_ + boffB[0]);                       \
        dst##1 = *(const s16x8*)(bt_ + boffB[1]);                       \
    } while (0)

#define MSTEP(bv, t) do {                                               \
        const ushort* ab_ = arow + (size_t)((t) >> 4) * SX + ((t) & 15) * 16; \
        s16x8 av0_ = *(const s16x8*)(ab_);                              \
        s16x8 av1_ = *(const s16x8*)(ab_ + (size_t)32 * SX);            \
        acc[0][0] = __builtin_amdgcn_mfma_f32_32x32x16_bf16(av0_, bv##0, acc[0][0], 0, 0, 0); \
        acc[0][1] = __builtin_amdgcn_mfma_f32_32x32x16_bf16(av0_, bv##1, acc[0][1], 0, 0, 0); \
        acc[1][0] = __builtin_amdgcn_mfma_f32_32x32x16_bf16(av1_, bv##0, acc[1][0], 0, 0, 0); \
        acc[1][1] = __builtin_amdgcn_mfma_f32_32x32x16_bf16(av1_, bv##1, acc[1][1], 0, 0, 0); \
    } while (0)

    s16x8 s0_0, s0_1, s1_0, s1_1, s2_0, s2_1, s3_0, s3_1;
    LOADB(s0_, 0);
    LOADB(s1_, 1);
    LOADB(s2_, 2);
    LOADB(s3_, 3);

    #pragma unroll 1
    for (int t = 0; t < 80; t += 4) {
        MSTEP(s0_, t);
        if (t + 4 < 80) LOADB(s0_, t + 4);
        MSTEP(s1_, t + 1);
        if (t + 5 < 80) LOADB(s1_, t + 5);
        MSTEP(s2_, t + 2);
        if (t + 6 < 80) LOADB(s2_, t + 6);
        MSTEP(s3_, t + 3);
        if (t + 7 < 80) LOADB(s3_, t + 7);
    }
#undef LOADB
#undef MSTEP

    // ---- epilogue: bias (i==0) + bf16 store.
    // D(32x32): col = lane&31, row = (reg&3) + 8*(reg>>2) + 4*(lane>>5)
    #pragma unroll
    for (int j = 0; j < 2; ++j) {
        int c = wid * 64 + j * 32 + l31;
        float bvv = (i == 0) ? bias[c] : 0.f;
        #pragma unroll
        for (int m = 0; m < 2; ++m)
            #pragma unroll
            for (int r = 0; r < 16; ++r) {
                int n = m * 32 + (r & 3) + 8 * (r >> 2) + 4 * kh;
                size_t z = (size_t)b * NN + n;
                hbuf[(z * DIRR + i) * COUT + c] = f2bf(acc[m][j][r] + bvv);
            }
    }
}

// ---------------------------------------------------------------------------
// K2a: norm, 4 z per block (2048 blocks). Writes hn2[c][z][i] + hn0[z][c].
// ---------------------------------------------------------------------------
__global__ __launch_bounds__(256) void norm_k(const ushort* __restrict__ hbuf,
                                              const float* __restrict__ afw,
                                              ushort* __restrict__ hn2,
                                              ushort* __restrict__ hn0)
{
    __shared__ float red[16];
    const int z0 = blockIdx.x * 4;
    const int c = threadIdx.x;
    const int lane = c & 63, w = c >> 6;

    float hv[4][16];
    #pragma unroll
    for (int zz = 0; zz < 4; ++zz)
        #pragma unroll
        for (int i = 0; i < 16; ++i)
            hv[zz][i] = bf2f(hbuf[((size_t)(z0 + zz) * DIRR + i) * COUT + c]);

    float s[4];
    #pragma unroll
    for (int zz = 0; zz < 4; ++zz) s[zz] = wave_sum(hv[zz][0]);
    if (lane == 0) {
        #pragma unroll
        for (int zz = 0; zz < 4; ++zz) red[zz * 4 + w] = s[zz];
    }
    __syncthreads();
    #pragma unroll
    for (int zz = 0; zz < 4; ++zz) {
        float m = (red[zz * 4] + red[zz * 4 + 1] + red[zz * 4 + 2] + red[zz * 4 + 3]) * (1.f / 256.f);
        hv[zz][0] -= m;
    }

    const float bal[4] = {0.25f, 1.f / 12.f, 1.f / 20.f, 1.f / 28.f};
    float var[4];
    #pragma unroll
    for (int zz = 0; zz < 4; ++zz) {
        float v = bal[0] * hv[zz][0] * hv[zz][0];
        #pragma unroll
        for (int i = 1; i < 16; ++i) {
            int li = (i < 4) ? 1 : (i < 9) ? 2 : 3;
            v += bal[li] * hv[zz][i] * hv[zz][i];
        }
        var[zz] = wave_sum(v);
    }
    __syncthreads();
    if (lane == 0) {
        #pragma unroll
        for (int zz = 0; zz < 4; ++zz) red[zz * 4 + w] = var[zz];
    }
    __syncthreads();
    float inv[4];
    #pragma unroll
    for (int zz = 0; zz < 4; ++zz)
        inv[zz] = rsqrtf((red[zz * 4] + red[zz * 4 + 1] + red[zz * 4 + 2] + red[zz * 4 + 3]) * (1.f / 256.f) + 1e-5f);

    float a0 = afw[c], a1 = afw[COUT + c], a2 = afw[2 * COUT + c], a3 = afw[3 * COUT + c];
    #pragma unroll
    for (int zz = 0; zz < 4; ++zz) {
        s16x8 o0, o1;
        #pragma unroll
        for (int i = 0; i < 16; ++i) {
            float al = (i == 0) ? a0 : (i < 4) ? a1 : (i < 9) ? a2 : a3;
            ushort ub = f2bf(hv[zz][i] * inv[zz] * al);
            if (i < 8) o0[i] = (short)ub; else o1[i - 8] = (short)ub;
        }
        ushort* dst = hn2 + ((size_t)c * ZTOT + z0 + zz) * DIRR;
        *(s16x8*)dst = o0;
        *(s16x8*)(dst + 8) = o1;
        hn0[(size_t)(z0 + zz) * COUT + c] = (ushort)(unsigned short)o0[0];
    }
}

// ---------------------------------------------------------------------------
// K2b: gate GEMM — gate[z,c] = silu(hn0[z,:] @ gwb[c,:] + gb[c]) -> out i=0.
// ---------------------------------------------------------------------------
__global__ __launch_bounds__(256) void gate_k(const ushort* __restrict__ hn0,
                                              const ushort* __restrict__ gwb,
                                              const float* __restrict__ gb,
                                              float* __restrict__ out)
{
    const int b = blockIdx.x;
    const int tid = threadIdx.x;
    const int lane = tid & 63, w = tid >> 6;
    const int lr = lane & 15, kb = lane >> 4;

    f32x4 acc[4][4];
    #pragma unroll
    for (int m = 0; m < 4; ++m)
        #pragma unroll
        for (int n = 0; n < 4; ++n) acc[m][n] = (f32x4){0.f, 0.f, 0.f, 0.f};

    #pragma unroll 1
    for (int ks = 0; ks < 8; ++ks) {
        s16x8 av[4], bv[4];
        #pragma unroll
        for (int m = 0; m < 4; ++m)
            av[m] = *(const s16x8*)(hn0 + ((size_t)(b * 64 + m * 16 + lr) * 256 + ks * 32 + kb * 8));
        #pragma unroll
        for (int n = 0; n < 4; ++n)
            bv[n] = *(const s16x8*)(gwb + ((size_t)(w * 64 + n * 16 + lr) * 256 + ks * 32 + kb * 8));
        #pragma unroll
        for (int m = 0; m < 4; ++m)
            #pragma unroll
            for (int n = 0; n < 4; ++n)
                acc[m][n] = __builtin_amdgcn_mfma_f32_16x16x32_bf16(av[m], bv[n], acc[m][n], 0, 0, 0);
    }

    #pragma unroll
    for (int n = 0; n < 4; ++n) {
        int c = w * 64 + n * 16 + lr;
        float gbc = gb[c];
        #pragma unroll
        for (int m = 0; m < 4; ++m)
            #pragma unroll
            for (int r = 0; r < 4; ++r) {
                int nrow = m * 16 + kb * 4 + r;
                out[((size_t)b * COUT + c) * (DIRR * NN) + nrow] = silu(acc[m][n][r] + gbc);
            }
    }
}

// ---------------------------------------------------------------------------
// K2c: grid einsums batched over c. Block = (c, 256-z tile), 4 waves. [r12]
// ---------------------------------------------------------------------------
__global__ __launch_bounds__(256) void grid_k(const ushort* __restrict__ hn2,
                                              const ushort* __restrict__ tgb,
                                              const ushort* __restrict__ fgTb,
                                              float* __restrict__ out)
{
    __shared__ __align__(16) char lds[36864 + 2048 + 2304];
    ushort* P_s  = (ushort*)lds;                    // [256][72] bf16
    float*  S_s  = (float*)lds;                     // [256][17] f32 (aliases P_s)
    ushort* tg_s = (ushort*)(lds + 36864);          // [64][16]
    ushort* fgT_s= (ushort*)(lds + 36864 + 2048);   // [16][72]

    const int bid = blockIdx.x;
    const int c  = bid & 255;
    const int zt = bid >> 8;
    const int z0 = zt * 256;
    const int tid = threadIdx.x;
    const int lane = tid & 63, w = tid >> 6;
    const int lr = lane & 15, kb = lane >> 4;

    #pragma unroll
    for (int q = 0; q < 4; ++q) {
        int idx = q * 256 + tid;            // 1024
        tg_s[idx] = tgb[idx];
        int i = idx >> 6, p = idx & 63;
        fgT_s[i * 72 + p] = fgTb[idx];
    }
    __syncthreads();

    // ---- GEMM1 ----
    f32x4 acc[4][4];
    #pragma unroll
    for (int m = 0; m < 4; ++m)
        #pragma unroll
        for (int n = 0; n < 4; ++n) acc[m][n] = (f32x4){0.f, 0.f, 0.f, 0.f};

    s16x8 bv[4];
    #pragma unroll
    for (int n = 0; n < 4; ++n)
        bv[n] = (kb < 2) ? *(const s16x8*)(tg_s + (n * 16 + lr) * 16 + kb * 8)
                         : (s16x8){0,0,0,0,0,0,0,0};
    #pragma unroll
    for (int m = 0; m < 4; ++m) {
        int zl = w * 64 + m * 16 + lr;
        s16x8 av = (kb < 2) ? *(const s16x8*)(hn2 + ((size_t)c * ZTOT + z0 + zl) * DIRR + kb * 8)
                            : (s16x8){0,0,0,0,0,0,0,0};
        #pragma unroll
        for (int n = 0; n < 4; ++n)
            acc[m][n] = __builtin_amdgcn_mfma_f32_16x16x32_bf16(av, bv[n], acc[m][n], 0, 0, 0);
    }

    // ---- silu -> P_s (wave-local region) ----
    #pragma unroll
    for (int m = 0; m < 4; ++m)
        #pragma unroll
        for (int n = 0; n < 4; ++n)
            #pragma unroll
            for (int r = 0; r < 4; ++r) {
                int zl = w * 64 + m * 16 + kb * 4 + r;
                int p  = n * 16 + lr;
                P_s[zl * 72 + p] = f2bf(silu(acc[m][n][r]));
            }

    // ---- GEMM2 (reads only this wave's P_s rows; in-wave DS ordering) ----
    f32x4 acc2[4];
    #pragma unroll
    for (int m = 0; m < 4; ++m) acc2[m] = (f32x4){0.f, 0.f, 0.f, 0.f};
    #pragma unroll
    for (int ks = 0; ks < 2; ++ks) {
        s16x8 bv2 = *(const s16x8*)(fgT_s + lr * 72 + ks * 32 + kb * 8);
        #pragma unroll
        for (int m = 0; m < 4; ++m) {
            s16x8 av2 = *(const s16x8*)(P_s + (w * 64 + m * 16 + lr) * 72 + ks * 32 + kb * 8);
            acc2[m] = __builtin_amdgcn_mfma_f32_16x16x32_bf16(av2, bv2, acc2[m], 0, 0, 0);
        }
    }

    __syncthreads();        // all waves done with P_s before S_s overwrites it

    #pragma unroll
    for (int m = 0; m < 4; ++m)
        #pragma unroll
        for (int r = 0; r < 4; ++r) {
            int zl = w * 64 + m * 16 + kb * 4 + r;
            S_s[zl * 17 + lr] = acc2[m][r];
        }
    __syncthreads();

    // ---- coalesced output: i = 1..15 ----
    const int bb = tid >> 6, n = tid & 63;
    const int b0 = zt * 4;
    const float* srow = S_s + (bb * 64 + n) * 17;
    float* obase = out + ((size_t)(b0 + bb) * COUT + c) * (DIRR * NN) + n;
    #pragma unroll
    for (int i = 1; i < 16; ++i)
        obase[i * NN] = srow[i];
}

// ---------------------------------------------------------------------------
// Fallback K2 (round-2 proven) if ws_size is too small for the split path.
// ---------------------------------------------------------------------------
__global__ __launch_bounds__(256) void post_k(const ushort* __restrict__ hbuf,
                                              const float* __restrict__ afw,
                                              const float* __restrict__ gw,
                                              const float* __restrict__ gb,
                                              const float* __restrict__ tg,
                                              const float* __restrict__ fg,
                                              float* __restrict__ out)
{
    __shared__ float h0s[COUT];
    __shared__ float red[4];
    __shared__ float tgs[64 * 16];
    __shared__ float fgs[64 * 16];

    int z = blockIdx.x;
    int c = threadIdx.x;
    int b = z >> 6, n = z & 63;
    int lane = c & 63, wid = c >> 6;

    for (int idx = c; idx < 1024; idx += 256) { tgs[idx] = tg[idx]; fgs[idx] = fg[idx]; }

    float hv[16];
    #pragma unroll
    for (int i = 0; i < 16; ++i)
        hv[i] = bf2f(hbuf[((size_t)z * DIRR + i) * COUT + c]);

    float s0 = wave_sum(hv[0]);
    if (lane == 0) red[wid] = s0;
    __syncthreads();
    float mean0 = (red[0] + red[1] + red[2] + red[3]) * (1.f / 256.f);
    hv[0] -= mean0;

    const float bal[4] = {0.25f, 1.f / 12.f, 1.f / 20.f, 1.f / 28.f};
    float var = bal[0] * hv[0] * hv[0];
    #pragma unroll
    for (int i = 1; i < 16; ++i) {
        int li = (i < 4) ? 1 : (i < 9) ? 2 : 3;
        var += bal[li] * hv[i] * hv[i];
    }
    float s1 = wave_sum(var);
    __syncthreads();
    if (lane == 0) red[wid] = s1;
    __syncthreads();
    float inv = rsqrtf((red[0] + red[1] + red[2] + red[3]) * (1.f / 256.f) + 1e-5f);

    float a0 = afw[c], a1 = afw[COUT + c], a2 = afw[2 * COUT + c], a3 = afw[3 * COUT + c];
    #pragma unroll
    for (int i = 0; i < 16; ++i) {
        float al = (i == 0) ? a0 : (i < 4) ? a1 : (i < 9) ? a2 : a3;
        hv[i] *= inv * al;
    }
    h0s[c] = hv[0];
    __syncthreads();

    float g = gb[c];
    const float4* gwr = (const float4*)(gw + (size_t)c * COUT);
    #pragma unroll 4
    for (int j = 0; j < 64; ++j) {
        float4 wv = gwr[j];
        g += h0s[4 * j] * wv.x + h0s[4 * j + 1] * wv.y + h0s[4 * j + 2] * wv.z + h0s[4 * j + 3] * wv.w;
    }
    float gate = silu(g);

    float s2a[16];
    #pragma unroll
    for (int i = 0; i < 16; ++i) s2a[i] = 0.f;
    #pragma unroll 1
    for (int p = 0; p < 64; ++p) {
        float gv = 0.f;
        #pragma unroll
        for (int i = 0; i < 16; ++i) gv += tgs[p * 16 + i] * hv[i];
        gv = silu(gv);
        #pragma unroll
        for (int i = 0; i < 16; ++i) s2a[i] += fgs[p * 16 + i] * gv;
    }

    float* ob = out + (size_t)b * COUT * DIRR * NN + (size_t)c * DIRR * NN + n;
    ob[0] = gate;
    #pragma unroll
    for (int i = 1; i < 16; ++i) ob[i * NN] = s2a[i];
}

extern "C" void kernel_launch(void* const* d_in, const int* in_sizes, int n_in,
                              void* d_out, int out_size, void* d_ws, size_t ws_size,
                              hipStream_t stream)
{
    const float* x    = (const float*)d_in[0];
    const float* w    = (const float*)d_in[1];
    const float* bias = (const float*)d_in[2];
    const float* afw  = (const float*)d_in[3];
    const float* gw   = (const float*)d_in[4];
    const float* gb   = (const float*)d_in[5];
    const float* tg   = (const float*)d_in[6];
    const float* fg   = (const float*)d_in[7];
    float* out = (float*)d_out;

    const size_t off_hbuf = 0;                         // 64 MiB
    const size_t off_wb   = 67108864;                  // 2.62 MiB
    const size_t off_hn2  = 69730304;                  // 64 MiB
    const size_t off_hn0  = off_hn2 + 67108864;        // 4 MiB
    const size_t off_gwb  = off_hn0 + 4194304;         // 128 KiB
    const size_t off_tgb  = off_gwb + 131072;          // 2 KiB
    const size_t off_fgT  = off_tgb + 2048;            // 2 KiB
    const size_t need     = off_fgT + 2048;            // ~134.6 MiB

    ushort* hbuf = (ushort*)((char*)d_ws + off_hbuf);
    ushort* wb   = (ushort*)((char*)d_ws + off_wb);

    if (ws_size >= need) {
        ushort* hn2  = (ushort*)((char*)d_ws + off_hn2);
        ushort* hn0  = (ushort*)((char*)d_ws + off_hn0);
        ushort* gwb  = (ushort*)((char*)d_ws + off_gwb);
        ushort* tgb  = (ushort*)((char*)d_ws + off_tgb);
        ushort* fgTb = (ushort*)((char*)d_ws + off_fgT);

        pack_all_k <<<5384, 256, 0, stream>>>(w, gw, tg, fg, wb, gwb, tgb, fgTb);
        conv_mfma_k<<<BB * DIRR, 256, 0, stream>>>(x, wb, bias, hbuf);
        norm_k     <<<ZTOT / 4, 256, 0, stream>>>(hbuf, afw, hn2, hn0);
        gate_k     <<<BB, 256, 0, stream>>>(hn0, gwb, gb, out);
        grid_k     <<<256 * (ZTOT / 256), 256, 0, stream>>>(hn2, tgb, fgTb, out);
    } else {
        pack_all_k <<<5120, 256, 0, stream>>>(w, gw, tg, fg, wb,
                                              (ushort*)((char*)d_ws + off_wb),
                                              (ushort*)((char*)d_ws + off_wb),
                                              (ushort*)((char*)d_ws + off_wb));
        conv_mfma_k<<<BB * DIRR, 256, 0, stream>>>(x, wb, bias, hbuf);
        post_k     <<<ZTOT, 256, 0, stream>>>(hbuf, afw, gw, gb, tg, fg, out);
    }
}

// Round 18
// 239.784 us; speedup vs baseline: 1.1138x; 1.0377x over previous
//
#include <hip/hip_runtime.h>
#include <hip/hip_bf16.h>

#define BB    128
#define CIN   256
#define COUT  256
#define NN    64
#define KW    5
#define DIRR  16
#define ZTOT  (BB*NN)
#define SX    264   // xs row stride (bf16): 528 B = 33*16 -> odd 16B-slot stride

typedef __attribute__((ext_vector_type(4)))  float f32x4;
typedef __attribute__((ext_vector_type(16))) float f32x16;
typedef __attribute__((ext_vector_type(8)))  short s16x8;

__device__ inline ushort f2bf(float f) {
    __hip_bfloat16 h = __float2bfloat16(f);
    return *(const ushort*)&h;
}
__device__ inline float bf2f(ushort u) {
    union { unsigned int ui; float f; } cv; cv.ui = ((unsigned int)u) << 16;
    return cv.f;
}
__device__ inline float wave_sum(float v) {
    #pragma unroll
    for (int o = 32; o > 0; o >>= 1) v += __shfl_down(v, o, 64);
    return v;
}
__device__ inline float silu(float x) { return x / (1.f + __expf(-x)); }

// ---------------------------------------------------------------------------
// K0: pack ALL weights in one launch.
// conv w -> wb32[l][t=80][c256][cin16]  (t = shift*16 + cin-chunk16)
// ---------------------------------------------------------------------------
__global__ __launch_bounds__(256) void pack_all_k(const float* __restrict__ w,
                                                  const float* __restrict__ gw,
                                                  const float* __restrict__ tg,
                                                  const float* __restrict__ fg,
                                                  ushort* __restrict__ wb,
                                                  ushort* __restrict__ gwb,
                                                  ushort* __restrict__ tgb,
                                                  ushort* __restrict__ fgTb)
{
    int idx = blockIdx.x * 256 + threadIdx.x;
    if (idx < 1310720) {
        int cl16 = idx & 15;
        int c    = (idx >> 4) & 255;
        int ch   = (idx >> 12) & 15;
        int lk   = idx >> 16;             // l*5 + k, 0..19
        int k    = lk % 5;
        int l    = lk / 5;
        int cin  = ch * 16 + cl16;
        wb[idx] = f2bf(w[(((size_t)(l * COUT + c) * CIN) + cin) * KW + k]);
        return;
    }
    int j2 = idx - 1310720;
    if (j2 < 65536) {
        gwb[j2] = f2bf(gw[j2]);
    } else if (j2 < 66560) {
        int j = j2 - 65536;
        tgb[j] = f2bf(tg[j]);
    } else if (j2 < 67584) {
        int j = j2 - 66560;                        // j = p*16 + i
        int p = j >> 4, i = j & 15;
        fgTb[i * 64 + p] = f2bf(fg[j]);
    }
}

// ---------------------------------------------------------------------------
// K1: conv as bf16 MFMA GEMM, 32x32x16, TWO batches per 512-thread block.
// M=128(n of 2 b's) x N=256(c), K = 80 steps of 16.
// 8 waves: each owns 32c x 64n x 2b (acc 64 AGPR). LDS = 2 planes (72 KB) ->
// 2 blocks/CU x 8 waves = 16 waves/CU (occupancy-neutral vs r17).
// One barrier. Each 16B B-load feeds 4 MFMAs -> B traffic 1.31 GB -> 655 MB.
// ---------------------------------------------------------------------------
__global__ __launch_bounds__(512, 4) void conv_mfma_k(const float* __restrict__ x,
                                                      const ushort* __restrict__ wb,
                                                      const float* __restrict__ bias,
                                                      ushort* __restrict__ hbuf)
{
    __shared__ __align__(16) ushort xs[2 * 68 * SX];    // ~71.8 KB

    const int tid  = threadIdx.x;
    const int lane = tid & 63;
    const int wid  = tid >> 6;                          // 0..7 -> c-slice of 32
    const int blk  = blockIdx.x;                        // 1024 blocks
    const int bp = blk >> 4, i = blk & 15;
    const int b0 = bp * 2;
    const int l = (i == 0) ? 0 : (i < 4) ? 1 : (i < 9) ? 2 : 3;

    // ---- stage x[b0..b0+1,:,i,:] -> xs[bb][2+n][cin], cin-major lanes
    {
        const int bb = tid >> 8;                        // 0/1: plane per 256-thread half
        const int t8 = tid & 255;
        const float4* xb = (const float4*)(x + (((size_t)(b0 + bb) * CIN) * DIRR + i) * NN);
        ushort* xp = xs + (size_t)bb * 68 * SX;
        #pragma unroll
        for (int p = 0; p < 16; ++p) {
            int cin = (t8 & 63) | ((p & 3) << 6);
            int nq  = ((t8 >> 6) << 2) | (p >> 2);
            float4 v = xb[(size_t)cin * (DIRR * NN / 4) + nq];
            ushort* dst = xp + (size_t)(2 + nq * 4) * SX + cin;
            dst[0]      = f2bf(v.x);
            dst[SX]     = f2bf(v.y);
            dst[2 * SX] = f2bf(v.z);
            dst[3 * SX] = f2bf(v.w);
        }
        // halo rows {0,1,66,67} x 2 planes, all SX cols: 2112 entries
        for (int idx2 = tid; idx2 < 2 * 4 * SX; idx2 += 512) {
            int pb  = idx2 >= 4 * SX;
            int rem = idx2 - pb * 4 * SX;
            int r4  = rem / SX;
            int col = rem - r4 * SX;
            int row = (r4 < 2) ? r4 : (64 + r4);
            xs[((size_t)pb * 68 + row) * SX + col] = 0;
        }
    }
    __syncthreads();                                    // the ONLY barrier

    f32x16 acc[2][2];                                   // [batch][m]
    #pragma unroll
    for (int bq = 0; bq < 2; ++bq)
        #pragma unroll
        for (int m = 0; m < 2; ++m)
            #pragma unroll
            for (int r = 0; r < 16; ++r) acc[bq][m][r] = 0.f;

    const int l31 = lane & 31;
    const int kh  = lane >> 5;

    const ushort* wl = wb + (size_t)l * (80 * 4096);
    const int boffB = (wid * 32 + l31) * 16 + kh * 8;
    const ushort* arow = xs + (size_t)l31 * SX + kh * 8;

#define LOADB(dst, t) do {                                              \
        dst = *(const s16x8*)(wl + ((size_t)(t) << 12) + boffB);        \
    } while (0)

#define MSTEP(bv, t) do {                                               \
        const ushort* ab_ = arow + (size_t)((t) >> 4) * SX + ((t) & 15) * 16; \
        s16x8 a00_ = *(const s16x8*)(ab_);                              \
        s16x8 a01_ = *(const s16x8*)(ab_ + (size_t)32 * SX);            \
        s16x8 a10_ = *(const s16x8*)(ab_ + (size_t)68 * SX);            \
        s16x8 a11_ = *(const s16x8*)(ab_ + (size_t)100 * SX);           \
        acc[0][0] = __builtin_amdgcn_mfma_f32_32x32x16_bf16(a00_, bv, acc[0][0], 0, 0, 0); \
        acc[0][1] = __builtin_amdgcn_mfma_f32_32x32x16_bf16(a01_, bv, acc[0][1], 0, 0, 0); \
        acc[1][0] = __builtin_amdgcn_mfma_f32_32x32x16_bf16(a10_, bv, acc[1][0], 0, 0, 0); \
        acc[1][1] = __builtin_amdgcn_mfma_f32_32x32x16_bf16(a11_, bv, acc[1][1], 0, 0, 0); \
    } while (0)

    s16x8 s0_, s1_, s2_, s3_;
    LOADB(s0_, 0);
    LOADB(s1_, 1);
    LOADB(s2_, 2);
    LOADB(s3_, 3);

    #pragma unroll 1
    for (int t = 0; t < 80; t += 4) {
        MSTEP(s0_, t);
        if (t + 4 < 80) LOADB(s0_, t + 4);
        MSTEP(s1_, t + 1);
        if (t + 5 < 80) LOADB(s1_, t + 5);
        MSTEP(s2_, t + 2);
        if (t + 6 < 80) LOADB(s2_, t + 6);
        MSTEP(s3_, t + 3);
        if (t + 7 < 80) LOADB(s3_, t + 7);
    }
#undef LOADB
#undef MSTEP

    // ---- epilogue: bias (i==0) + bf16 store.
    // D(32x32): col = lane&31, row = (reg&3) + 8*(reg>>2) + 4*(lane>>5)
    const int c = wid * 32 + l31;
    const float bvv = (i == 0) ? bias[c] : 0.f;
    #pragma unroll
    for (int bq = 0; bq < 2; ++bq)
        #pragma unroll
        for (int m = 0; m < 2; ++m)
            #pragma unroll
            for (int r = 0; r < 16; ++r) {
                int n = m * 32 + (r & 3) + 8 * (r >> 2) + 4 * kh;
                size_t z = (size_t)(b0 + bq) * NN + n;
                hbuf[(z * DIRR + i) * COUT + c] = f2bf(acc[bq][m][r] + bvv);
            }
}

// ---------------------------------------------------------------------------
// K2a: norm, 4 z per block (2048 blocks). Writes hn2[c][z][i] + hn0[z][c].
// ---------------------------------------------------------------------------
__global__ __launch_bounds__(256) void norm_k(const ushort* __restrict__ hbuf,
                                              const float* __restrict__ afw,
                                              ushort* __restrict__ hn2,
                                              ushort* __restrict__ hn0)
{
    __shared__ float red[16];
    const int z0 = blockIdx.x * 4;
    const int c = threadIdx.x;
    const int lane = c & 63, w = c >> 6;

    float hv[4][16];
    #pragma unroll
    for (int zz = 0; zz < 4; ++zz)
        #pragma unroll
        for (int i = 0; i < 16; ++i)
            hv[zz][i] = bf2f(hbuf[((size_t)(z0 + zz) * DIRR + i) * COUT + c]);

    float s[4];
    #pragma unroll
    for (int zz = 0; zz < 4; ++zz) s[zz] = wave_sum(hv[zz][0]);
    if (lane == 0) {
        #pragma unroll
        for (int zz = 0; zz < 4; ++zz) red[zz * 4 + w] = s[zz];
    }
    __syncthreads();
    #pragma unroll
    for (int zz = 0; zz < 4; ++zz) {
        float m = (red[zz * 4] + red[zz * 4 + 1] + red[zz * 4 + 2] + red[zz * 4 + 3]) * (1.f / 256.f);
        hv[zz][0] -= m;
    }

    const float bal[4] = {0.25f, 1.f / 12.f, 1.f / 20.f, 1.f / 28.f};
    float var[4];
    #pragma unroll
    for (int zz = 0; zz < 4; ++zz) {
        float v = bal[0] * hv[zz][0] * hv[zz][0];
        #pragma unroll
        for (int i = 1; i < 16; ++i) {
            int li = (i < 4) ? 1 : (i < 9) ? 2 : 3;
            v += bal[li] * hv[zz][i] * hv[zz][i];
        }
        var[zz] = wave_sum(v);
    }
    __syncthreads();
    if (lane == 0) {
        #pragma unroll
        for (int zz = 0; zz < 4; ++zz) red[zz * 4 + w] = var[zz];
    }
    __syncthreads();
    float inv[4];
    #pragma unroll
    for (int zz = 0; zz < 4; ++zz)
        inv[zz] = rsqrtf((red[zz * 4] + red[zz * 4 + 1] + red[zz * 4 + 2] + red[zz * 4 + 3]) * (1.f / 256.f) + 1e-5f);

    float a0 = afw[c], a1 = afw[COUT + c], a2 = afw[2 * COUT + c], a3 = afw[3 * COUT + c];
    #pragma unroll
    for (int zz = 0; zz < 4; ++zz) {
        s16x8 o0, o1;
        #pragma unroll
        for (int i = 0; i < 16; ++i) {
            float al = (i == 0) ? a0 : (i < 4) ? a1 : (i < 9) ? a2 : a3;
            ushort ub = f2bf(hv[zz][i] * inv[zz] * al);
            if (i < 8) o0[i] = (short)ub; else o1[i - 8] = (short)ub;
        }
        ushort* dst = hn2 + ((size_t)c * ZTOT + z0 + zz) * DIRR;
        *(s16x8*)dst = o0;
        *(s16x8*)(dst + 8) = o1;
        hn0[(size_t)(z0 + zz) * COUT + c] = (ushort)(unsigned short)o0[0];
    }
}

// ---------------------------------------------------------------------------
// K2b: gate GEMM — gate[z,c] = silu(hn0[z,:] @ gwb[c,:] + gb[c]) -> out i=0.
// ---------------------------------------------------------------------------
__global__ __launch_bounds__(256) void gate_k(const ushort* __restrict__ hn0,
                                              const ushort* __restrict__ gwb,
                                              const float* __restrict__ gb,
                                              float* __restrict__ out)
{
    const int b = blockIdx.x;
    const int tid = threadIdx.x;
    const int lane = tid & 63, w = tid >> 6;
    const int lr = lane & 15, kb = lane >> 4;

    f32x4 acc[4][4];
    #pragma unroll
    for (int m = 0; m < 4; ++m)
        #pragma unroll
        for (int n = 0; n < 4; ++n) acc[m][n] = (f32x4){0.f, 0.f, 0.f, 0.f};

    #pragma unroll 1
    for (int ks = 0; ks < 8; ++ks) {
        s16x8 av[4], bv[4];
        #pragma unroll
        for (int m = 0; m < 4; ++m)
            av[m] = *(const s16x8*)(hn0 + ((size_t)(b * 64 + m * 16 + lr) * 256 + ks * 32 + kb * 8));
        #pragma unroll
        for (int n = 0; n < 4; ++n)
            bv[n] = *(const s16x8*)(gwb + ((size_t)(w * 64 + n * 16 + lr) * 256 + ks * 32 + kb * 8));
        #pragma unroll
        for (int m = 0; m < 4; ++m)
            #pragma unroll
            for (int n = 0; n < 4; ++n)
                acc[m][n] = __builtin_amdgcn_mfma_f32_16x16x32_bf16(av[m], bv[n], acc[m][n], 0, 0, 0);
    }

    #pragma unroll
    for (int n = 0; n < 4; ++n) {
        int c = w * 64 + n * 16 + lr;
        float gbc = gb[c];
        #pragma unroll
        for (int m = 0; m < 4; ++m)
            #pragma unroll
            for (int r = 0; r < 4; ++r) {
                int nrow = m * 16 + kb * 4 + r;
                out[((size_t)b * COUT + c) * (DIRR * NN) + nrow] = silu(acc[m][n][r] + gbc);
            }
    }
}

// ---------------------------------------------------------------------------
// K2c: grid einsums batched over c. Block = (c, 256-z tile), 4 waves. [r12]
// ---------------------------------------------------------------------------
__global__ __launch_bounds__(256) void grid_k(const ushort* __restrict__ hn2,
                                              const ushort* __restrict__ tgb,
                                              const ushort* __restrict__ fgTb,
                                              float* __restrict__ out)
{
    __shared__ __align__(16) char lds[36864 + 2048 + 2304];
    ushort* P_s  = (ushort*)lds;                    // [256][72] bf16
    float*  S_s  = (float*)lds;                     // [256][17] f32 (aliases P_s)
    ushort* tg_s = (ushort*)(lds + 36864);          // [64][16]
    ushort* fgT_s= (ushort*)(lds + 36864 + 2048);   // [16][72]

    const int bid = blockIdx.x;
    const int c  = bid & 255;
    const int zt = bid >> 8;
    const int z0 = zt * 256;
    const int tid = threadIdx.x;
    const int lane = tid & 63, w = tid >> 6;
    const int lr = lane & 15, kb = lane >> 4;

    #pragma unroll
    for (int q = 0; q < 4; ++q) {
        int idx = q * 256 + tid;            // 1024
        tg_s[idx] = tgb[idx];
        int i = idx >> 6, p = idx & 63;
        fgT_s[i * 72 + p] = fgTb[idx];
    }
    __syncthreads();

    // ---- GEMM1 ----
    f32x4 acc[4][4];
    #pragma unroll
    for (int m = 0; m < 4; ++m)
        #pragma unroll
        for (int n = 0; n < 4; ++n) acc[m][n] = (f32x4){0.f, 0.f, 0.f, 0.f};

    s16x8 bv[4];
    #pragma unroll
    for (int n = 0; n < 4; ++n)
        bv[n] = (kb < 2) ? *(const s16x8*)(tg_s + (n * 16 + lr) * 16 + kb * 8)
                         : (s16x8){0,0,0,0,0,0,0,0};
    #pragma unroll
    for (int m = 0; m < 4; ++m) {
        int zl = w * 64 + m * 16 + lr;
        s16x8 av = (kb < 2) ? *(const s16x8*)(hn2 + ((size_t)c * ZTOT + z0 + zl) * DIRR + kb * 8)
                            : (s16x8){0,0,0,0,0,0,0,0};
        #pragma unroll
        for (int n = 0; n < 4; ++n)
            acc[m][n] = __builtin_amdgcn_mfma_f32_16x16x32_bf16(av, bv[n], acc[m][n], 0, 0, 0);
    }

    // ---- silu -> P_s (wave-local region) ----
    #pragma unroll
    for (int m = 0; m < 4; ++m)
        #pragma unroll
        for (int n = 0; n < 4; ++n)
            #pragma unroll
            for (int r = 0; r < 4; ++r) {
                int zl = w * 64 + m * 16 + kb * 4 + r;
                int p  = n * 16 + lr;
                P_s[zl * 72 + p] = f2bf(silu(acc[m][n][r]));
            }

    // ---- GEMM2 (reads only this wave's P_s rows; in-wave DS ordering) ----
    f32x4 acc2[4];
    #pragma unroll
    for (int m = 0; m < 4; ++m) acc2[m] = (f32x4){0.f, 0.f, 0.f, 0.f};
    #pragma unroll
    for (int ks = 0; ks < 2; ++ks) {
        s16x8 bv2 = *(const s16x8*)(fgT_s + lr * 72 + ks * 32 + kb * 8);
        #pragma unroll
        for (int m = 0; m < 4; ++m) {
            s16x8 av2 = *(const s16x8*)(P_s + (w * 64 + m * 16 + lr) * 72 + ks * 32 + kb * 8);
            acc2[m] = __builtin_amdgcn_mfma_f32_16x16x32_bf16(av2, bv2, acc2[m], 0, 0, 0);
        }
    }

    __syncthreads();        // all waves done with P_s before S_s overwrites it

    #pragma unroll
    for (int m = 0; m < 4; ++m)
        #pragma unroll
        for (int r = 0; r < 4; ++r) {
            int zl = w * 64 + m * 16 + kb * 4 + r;
            S_s[zl * 17 + lr] = acc2[m][r];
        }
    __syncthreads();

    // ---- coalesced output: i = 1..15 ----
    const int bb = tid >> 6, n = tid & 63;
    const int b0 = zt * 4;
    const float* srow = S_s + (bb * 64 + n) * 17;
    float* obase = out + ((size_t)(b0 + bb) * COUT + c) * (DIRR * NN) + n;
    #pragma unroll
    for (int i = 1; i < 16; ++i)
        obase[i * NN] = srow[i];
}

// ---------------------------------------------------------------------------
// Fallback K2 (round-2 proven) if ws_size is too small for the split path.
// ---------------------------------------------------------------------------
__global__ __launch_bounds__(256) void post_k(const ushort* __restrict__ hbuf,
                                              const float* __restrict__ afw,
                                              const float* __restrict__ gw,
                                              const float* __restrict__ gb,
                                              const float* __restrict__ tg,
                                              const float* __restrict__ fg,
                                              float* __restrict__ out)
{
    __shared__ float h0s[COUT];
    __shared__ float red[4];
    __shared__ float tgs[64 * 16];
    __shared__ float fgs[64 * 16];

    int z = blockIdx.x;
    int c = threadIdx.x;
    int b = z >> 6, n = z & 63;
    int lane = c & 63, wid = c >> 6;

    for (int idx = c; idx < 1024; idx += 256) { tgs[idx] = tg[idx]; fgs[idx] = fg[idx]; }

    float hv[16];
    #pragma unroll
    for (int i = 0; i < 16; ++i)
        hv[i] = bf2f(hbuf[((size_t)z * DIRR + i) * COUT + c]);

    float s0 = wave_sum(hv[0]);
    if (lane == 0) red[wid] = s0;
    __syncthreads();
    float mean0 = (red[0] + red[1] + red[2] + red[3]) * (1.f / 256.f);
    hv[0] -= mean0;

    const float bal[4] = {0.25f, 1.f / 12.f, 1.f / 20.f, 1.f / 28.f};
    float var = bal[0] * hv[0] * hv[0];
    #pragma unroll
    for (int i = 1; i < 16; ++i) {
        int li = (i < 4) ? 1 : (i < 9) ? 2 : 3;
        var += bal[li] * hv[i] * hv[i];
    }
    float s1 = wave_sum(var);
    __syncthreads();
    if (lane == 0) red[wid] = s1;
    __syncthreads();
    float inv = rsqrtf((red[0] + red[1] + red[2] + red[3]) * (1.f / 256.f) + 1e-5f);

    float a0 = afw[c], a1 = afw[COUT + c], a2 = afw[2 * COUT + c], a3 = afw[3 * COUT + c];
    #pragma unroll
    for (int i = 0; i < 16; ++i) {
        float al = (i == 0) ? a0 : (i < 4) ? a1 : (i < 9) ? a2 : a3;
        hv[i] *= inv * al;
    }
    h0s[c] = hv[0];
    __syncthreads();

    float g = gb[c];
    const float4* gwr = (const float4*)(gw + (size_t)c * COUT);
    #pragma unroll 4
    for (int j = 0; j < 64; ++j) {
        float4 wv = gwr[j];
        g += h0s[4 * j] * wv.x + h0s[4 * j + 1] * wv.y + h0s[4 * j + 2] * wv.z + h0s[4 * j + 3] * wv.w;
    }
    float gate = silu(g);

    float s2a[16];
    #pragma unroll
    for (int i = 0; i < 16; ++i) s2a[i] = 0.f;
    #pragma unroll 1
    for (int p = 0; p < 64; ++p) {
        float gv = 0.f;
        #pragma unroll
        for (int i = 0; i < 16; ++i) gv += tgs[p * 16 + i] * hv[i];
        gv = silu(gv);
        #pragma unroll
        for (int i = 0; i < 16; ++i) s2a[i] += fgs[p * 16 + i] * gv;
    }

    float* ob = out + (size_t)b * COUT * DIRR * NN + (size_t)c * DIRR * NN + n;
    ob[0] = gate;
    #pragma unroll
    for (int i = 1; i < 16; ++i) ob[i * NN] = s2a[i];
}

extern "C" void kernel_launch(void* const* d_in, const int* in_sizes, int n_in,
                              void* d_out, int out_size, void* d_ws, size_t ws_size,
                              hipStream_t stream)
{
    const float* x    = (const float*)d_in[0];
    const float* w    = (const float*)d_in[1];
    const float* bias = (const float*)d_in[2];
    const float* afw  = (const float*)d_in[3];
    const float* gw   = (const float*)d_in[4];
    const float* gb   = (const float*)d_in[5];
    const float* tg   = (const float*)d_in[6];
    const float* fg   = (const float*)d_in[7];
    float* out = (float*)d_out;

    const size_t off_hbuf = 0;                         // 64 MiB
    const size_t off_wb   = 67108864;                  // 2.62 MiB
    const size_t off_hn2  = 69730304;                  // 64 MiB
    const size_t off_hn0  = off_hn2 + 67108864;        // 4 MiB
    const size_t off_gwb  = off_hn0 + 4194304;         // 128 KiB
    const size_t off_tgb  = off_gwb + 131072;          // 2 KiB
    const size_t off_fgT  = off_tgb + 2048;            // 2 KiB
    const size_t need     = off_fgT + 2048;            // ~134.6 MiB

    ushort* hbuf = (ushort*)((char*)d_ws + off_hbuf);
    ushort* wb   = (ushort*)((char*)d_ws + off_wb);

    if (ws_size >= need) {
        ushort* hn2  = (ushort*)((char*)d_ws + off_hn2);
        ushort* hn0  = (ushort*)((char*)d_ws + off_hn0);
        ushort* gwb  = (ushort*)((char*)d_ws + off_gwb);
        ushort* tgb  = (ushort*)((char*)d_ws + off_tgb);
        ushort* fgTb = (ushort*)((char*)d_ws + off_fgT);

        pack_all_k <<<5384, 256, 0, stream>>>(w, gw, tg, fg, wb, gwb, tgb, fgTb);
        conv_mfma_k<<<(BB / 2) * DIRR, 512, 0, stream>>>(x, wb, bias, hbuf);
        norm_k     <<<ZTOT / 4, 256, 0, stream>>>(hbuf, afw, hn2, hn0);
        gate_k     <<<BB, 256, 0, stream>>>(hn0, gwb, gb, out);
        grid_k     <<<256 * (ZTOT / 256), 256, 0, stream>>>(hn2, tgb, fgTb, out);
    } else {
        pack_all_k <<<5120, 256, 0, stream>>>(w, gw, tg, fg, wb,
                                              (ushort*)((char*)d_ws + off_wb),
                                              (ushort*)((char*)d_ws + off_wb),
                                              (ushort*)((char*)d_ws + off_wb));
        conv_mfma_k<<<(BB / 2) * DIRR, 512, 0, stream>>>(x, wb, bias, hbuf);
        post_k     <<<ZTOT, 256, 0, stream>>>(hbuf, afw, gw, gb, tg, fg, out);
    }
}